// Round 1
// baseline (85.540 us; speedup 1.0000x reference)
//
#include <hip/hip_runtime.h>
#include <hip/hip_bf16.h>

// Problem constants
#define BSZ   131072
#define DIM   256
#define BM    64
#define BK    32
#define NT    512            // 8 waves
#define KITERS (DIM / BK)    // 8
#define GRID  (BSZ / BM)     // 2048

// LDS layout per buffer (bytes):
//   z tile  : [64 rows][80B]  (32 bf16 + 16B pad)        = 5120
//   Wmu tile: [256 rows][64B] (32 bf16, slot-swizzled)   = 16384  @ 5120
//   Wsd tile: same                                        = 16384  @ 21504
#define BUFB   37888
#define WOFF   5120
#define WSOFF  16384   // extra offset of Wsd tile past Wmu tile

typedef __attribute__((ext_vector_type(8))) short bf16x8;
typedef __attribute__((ext_vector_type(4))) float f32x4;
typedef __attribute__((ext_vector_type(4))) unsigned short u16x4;

__device__ __forceinline__ unsigned short f2bf(float f) {
  unsigned u = __builtin_bit_cast(unsigned, f);
  return (unsigned short)((u + 0x7FFFu + ((u >> 16) & 1u)) >> 16);
}

// swizzle mask for W tiles: physical_slot = logical_k8 ^ mask(j), 16B slots, 4 per 64B row
__device__ __forceinline__ int wmask(int j) { return (j ^ (j >> 2)) & 3; }

// ---------------- prep: f32 W -> bf16 W in workspace ----------------
__global__ void prep_kernel(const float* __restrict__ Wmu, const float* __restrict__ Wsd,
                            unsigned short* __restrict__ wm, unsigned short* __restrict__ wsd) {
  const int i = (blockIdx.x * blockDim.x + threadIdx.x) * 4;  // 16384 threads * 4 = 65536
  f32x4 a = *(const f32x4*)(Wmu + i);
  f32x4 b = *(const f32x4*)(Wsd + i);
  u16x4 pa, pb;
#pragma unroll
  for (int e = 0; e < 4; ++e) { pa[e] = f2bf(a[e]); pb[e] = f2bf(b[e]); }
  *(u16x4*)(wm + i)  = pa;
  *(u16x4*)(wsd + i) = pb;
}

// ---------------- main fused kernel ----------------
__global__ __launch_bounds__(NT, 4)
void main_kernel(const float* __restrict__ z,
                 const unsigned short* __restrict__ wm,
                 const unsigned short* __restrict__ wsd,
                 const float* __restrict__ bmu,
                 const float* __restrict__ bsd,
                 float* __restrict__ out,
                 double* __restrict__ partials) {
  __shared__ unsigned char smem[2 * BUFB];
  __shared__ float redbuf[8];

  const int t    = threadIdx.x;
  const int lane = t & 63;
  const int wave = t >> 6;       // 0..7
  const int bm   = blockIdx.x;   // 0..2047

  // ---- W staging addressing (global_load_lds, source pre-swizzled) ----
  // issue 0 covers LDS bytes [wave*1024 + lane*16] of the 16KB tile; issue 1 adds 8192.
  const int jw   = wave * 16 + (lane >> 2);          // row this lane's 16B chunk belongs to (issue 0)
  const int slot = lane & 3;                          // physical 16B slot within the 64B row
  const int k8l  = slot ^ wmask(jw);                  // logical k-chunk stored at that slot
  const int wsrc0 = jw * DIM + k8l * 8;               // + k0 ; issue1: + 128*DIM = +32768

  // ---- z staging addressing (reg-staged f32 -> bf16, padded rows) ----
  const int zr = t >> 3, kc = t & 7;
  const float* zsrc = z + (bm * BM + zr) * DIM + kc * 4;  // + k0
  const int zoff = zr * 80 + kc * 8;                      // + buf*BUFB

  // ---- compute-side LDS offsets ----
  int aoff[4];
#pragma unroll
  for (int m = 0; m < 4; ++m)
    aoff[m] = (m * 16 + (lane & 15)) * 80 + (lane >> 4) * 16;
  int boff[2];
#pragma unroll
  for (int n = 0; n < 2; ++n) {
    const int jl = wave * 32 + n * 16 + (lane & 15);
    boff[n] = WOFF + jl * 64 + (((lane >> 4) ^ wmask(jl)) << 4);
  }

  f32x4 accm[4][2], accl[4][2];
#pragma unroll
  for (int m = 0; m < 4; ++m)
#pragma unroll
    for (int n = 0; n < 2; ++n) {
      accm[m][n] = (f32x4)0.0f;
      accl[m][n] = (f32x4)0.0f;
    }

  // ---- prologue: stage tile 0 into buffer 0 ----
  {
    unsigned char* buf0 = smem;
    __builtin_amdgcn_global_load_lds((const void*)(wm + wsrc0),          (void*)(buf0 + WOFF + wave * 1024),                16, 0, 0);
    __builtin_amdgcn_global_load_lds((const void*)(wm + wsrc0 + 32768),  (void*)(buf0 + WOFF + wave * 1024 + 8192),         16, 0, 0);
    __builtin_amdgcn_global_load_lds((const void*)(wsd + wsrc0),         (void*)(buf0 + WOFF + WSOFF + wave * 1024),        16, 0, 0);
    __builtin_amdgcn_global_load_lds((const void*)(wsd + wsrc0 + 32768), (void*)(buf0 + WOFF + WSOFF + wave * 1024 + 8192), 16, 0, 0);
    f32x4 zv = *(const f32x4*)zsrc;
    u16x4 p;
#pragma unroll
    for (int e = 0; e < 4; ++e) p[e] = f2bf(zv[e]);
    *(u16x4*)(buf0 + zoff) = p;
  }
  __syncthreads();

  // ---- K loop: double-buffered ----
  for (int it = 0; it < KITERS; ++it) {
    const int cur = it & 1;
    unsigned char* bufc = smem + cur * BUFB;
    unsigned char* bufn = smem + (cur ^ 1) * BUFB;

    f32x4 zv;
    if (it + 1 < KITERS) {
      const int k0 = (it + 1) * BK;
      __builtin_amdgcn_global_load_lds((const void*)(wm + wsrc0 + k0),          (void*)(bufn + WOFF + wave * 1024),                16, 0, 0);
      __builtin_amdgcn_global_load_lds((const void*)(wm + wsrc0 + 32768 + k0),  (void*)(bufn + WOFF + wave * 1024 + 8192),         16, 0, 0);
      __builtin_amdgcn_global_load_lds((const void*)(wsd + wsrc0 + k0),         (void*)(bufn + WOFF + WSOFF + wave * 1024),        16, 0, 0);
      __builtin_amdgcn_global_load_lds((const void*)(wsd + wsrc0 + 32768 + k0), (void*)(bufn + WOFF + WSOFF + wave * 1024 + 8192), 16, 0, 0);
      zv = *(const f32x4*)(zsrc + k0);   // issue early; consumed after MFMAs (T14 split)
    }

    // compute on bufc
    bf16x8 a[4];
#pragma unroll
    for (int m = 0; m < 4; ++m) a[m] = *(const bf16x8*)(bufc + aoff[m]);
#pragma unroll
    for (int n = 0; n < 2; ++n) {
      const bf16x8 bmv = *(const bf16x8*)(bufc + boff[n]);
      const bf16x8 bsv = *(const bf16x8*)(bufc + boff[n] + WSOFF);
#pragma unroll
      for (int m = 0; m < 4; ++m) {
        accm[m][n] = __builtin_amdgcn_mfma_f32_16x16x32_bf16(a[m], bmv, accm[m][n], 0, 0, 0);
        accl[m][n] = __builtin_amdgcn_mfma_f32_16x16x32_bf16(a[m], bsv, accl[m][n], 0, 0, 0);
      }
    }

    if (it + 1 < KITERS) {
      u16x4 p;
#pragma unroll
      for (int e = 0; e < 4; ++e) p[e] = f2bf(zv[e]);
      *(u16x4*)(bufn + zoff) = p;
    }
    __syncthreads();
  }

  // ---- epilogue: bias + relu + KL + store mu ----
  float klp = 0.0f;
#pragma unroll
  for (int n = 0; n < 2; ++n) {
    const int col = wave * 32 + n * 16 + (lane & 15);
    const float bmv = bmu[col];
    const float bsv = bsd[col];
#pragma unroll
    for (int m = 0; m < 4; ++m) {
      const int row = bm * BM + m * 16 + (lane >> 4) * 4;
#pragma unroll
      for (int r = 0; r < 4; ++r) {
        float mu = fmaxf(accm[m][n][r] + bmv, 0.0f);
        float ls = fmaxf(accl[m][n][r] + bsv, 0.0f);
        float iv = __expf(-2.0f * ls);
        klp += fmaf(mu * mu, iv, iv) + 2.0f * ls;   // (1+mu^2)*iv + 2*ls ; the -1 is folded below
        out[(row + r) * DIM + col] = mu;
      }
    }
  }
  klp = 0.5f * (klp - 32.0f);   // 32 elements per thread, each owes a -1

  // wave -> block reduction
#pragma unroll
  for (int off = 32; off > 0; off >>= 1) klp += __shfl_down(klp, off);
  if (lane == 0) redbuf[wave] = klp;
  __syncthreads();
  if (t == 0) {
    float s = 0.0f;
#pragma unroll
    for (int i = 0; i < 8; ++i) s += redbuf[i];
    partials[bm] = (double)s;
  }
}

// ---------------- finalize: reduce per-block partials -> kl ----------------
__global__ void fin_kernel(const double* __restrict__ partials, float* __restrict__ out) {
  __shared__ double red[256];
  double s = 0.0;
  for (int i = threadIdx.x; i < GRID; i += 256) s += partials[i];
  red[threadIdx.x] = s;
  __syncthreads();
  for (int st = 128; st > 0; st >>= 1) {
    if ((int)threadIdx.x < st) red[threadIdx.x] += red[threadIdx.x + st];
    __syncthreads();
  }
  if (threadIdx.x == 0) out[(size_t)BSZ * DIM] = (float)(red[0] / (double)BSZ);
}

// ---------------- launch ----------------
// workspace layout: [0,16KB) 2048 double partials ; [16KB,+128KB) Wmu bf16 ; then Wsd bf16.
// requires ws_size >= 278528 bytes.
extern "C" void kernel_launch(void* const* d_in, const int* in_sizes, int n_in,
                              void* d_out, int out_size, void* d_ws, size_t ws_size,
                              hipStream_t stream) {
  const float* z   = (const float*)d_in[0];
  const float* Wmu = (const float*)d_in[1];
  const float* bmu = (const float*)d_in[2];
  const float* Wsd = (const float*)d_in[3];
  const float* bsd = (const float*)d_in[4];
  float* out = (float*)d_out;

  double* partials  = (double*)d_ws;
  unsigned short* wm  = (unsigned short*)((char*)d_ws + 16384);
  unsigned short* wsd = wm + DIM * DIM;

  prep_kernel<<<64, 256, 0, stream>>>(Wmu, Wsd, wm, wsd);
  main_kernel<<<GRID, NT, 0, stream>>>(z, wm, wsd, bmu, bsd, out, partials);
  fin_kernel<<<1, 256, 0, stream>>>(partials, out);
}